// Round 3
// baseline (155.793 us; speedup 1.0000x reference)
//
#include <hip/hip_runtime.h>
#include <math.h>

#define NA_ 128
#define F_ 256
#define VBS_ 128
#define GAMMA_ 1.5f
#define EPS_ 1e-5f

typedef __attribute__((ext_vector_type(8))) short short8;
typedef __attribute__((ext_vector_type(4))) float f32x4;

static __device__ __forceinline__ unsigned f2bf(float f) {
    unsigned u = __float_as_uint(f);
    return (u + 0x7FFFu + ((u >> 16) & 1u)) >> 16;   // RNE bf16
}
static __device__ __forceinline__ float bflo(unsigned u) { return __uint_as_float(u << 16); }
static __device__ __forceinline__ float bfhi(unsigned u) { return __uint_as_float(u & 0xFFFF0000u); }

// ---------------- kernel 0: W f32 -> bf16 (64 KB, one-time) ----------------
__global__ void k0_cvt_w(const float* __restrict__ W, unsigned short* __restrict__ Wb) {
    int i = blockIdx.x * 256 + threadIdx.x;          // 8192 groups of 4
    float4 v = reinterpret_cast<const float4*>(W)[i];
    uint2 o;
    o.x = f2bf(v.x) | (f2bf(v.y) << 16);
    o.y = f2bf(v.z) | (f2bf(v.w) << 16);
    reinterpret_cast<uint2*>(Wb)[i] = o;
}

// ---------------- fully fused: GEMM + ghost-BN + sparsemax + outputs ----------------
// block = one virtual-batch chunk (128 rows), 512 threads = 8 waves (2 row-halves x 4 col-quarters)
__global__ __launch_bounds__(512, 4) void k_fused(
    const float* __restrict__ a, const unsigned short* __restrict__ Wb,
    const float* __restrict__ bnw, const float* __restrict__ bnb,
    const float* __restrict__ prior,
    float* __restrict__ out_m, float* __restrict__ out_np)
{
    __shared__ unsigned short albuf[VBS_ * NA_];   // 32 KB bf16, XOR-swizzled 16B units
    __shared__ float sbuf[2][4][4][16];            // BN partial sums  [wr][wc][ft][lr]
    __shared__ float qbuf[2][4][4][16];            // BN partial sumsq
    __shared__ float rowsum[VBS_][4];              // per-row partials [row][wc]
    __shared__ float rowmax[VBS_][4];
    __shared__ float tau_s[VBS_];
    __shared__ float zrow[F_];                     // slow-path sort buffer
    __shared__ int nflag;

    const int tid = threadIdx.x;
    const int lane = tid & 63, wid = tid >> 6;
    const int wr = wid >> 2, wc = wid & 3;         // wave = (row-half, col-quarter)
    const int lr = lane & 15, lg = lane >> 4;
    const size_t rowbase = (size_t)blockIdx.x * VBS_;

    if (tid == 0) nflag = 0;

    // ---- stage a (f32) -> bf16 LDS, swizzle byte ^= ((row&7)<<4), 16B granularity
    #pragma unroll
    for (int i = 0; i < 4; ++i) {
        int seg = tid + 512 * i;                   // 2048 segs of 8 elems
        int row = seg >> 4, ks = seg & 15;
        const float4* g = reinterpret_cast<const float4*>(a + (rowbase + row) * NA_ + ks * 8);
        float4 v0 = g[0], v1 = g[1];
        uint4 pk;
        pk.x = f2bf(v0.x) | (f2bf(v0.y) << 16);
        pk.y = f2bf(v0.z) | (f2bf(v0.w) << 16);
        pk.z = f2bf(v1.x) | (f2bf(v1.y) << 16);
        pk.w = f2bf(v1.z) | (f2bf(v1.w) << 16);
        int byte = (row * 256 + ks * 16) ^ ((row & 7) << 4);
        *reinterpret_cast<uint4*>(reinterpret_cast<char*>(albuf) + byte) = pk;
    }
    __syncthreads();

    // ---- MFMA: wave computes rows [wr*64, wr*64+64) x cols [wc*64, wc*64+64)
    f32x4 acc[4][4];
    #pragma unroll
    for (int m = 0; m < 4; ++m)
        #pragma unroll
        for (int ft = 0; ft < 4; ++ft)
            acc[m][ft] = (f32x4){0.f, 0.f, 0.f, 0.f};

    // linear bias b cancels through BN -> skipped
    #pragma unroll
    for (int kt = 0; kt < 4; ++kt) {
        short8 bfr[4];
        #pragma unroll
        for (int ft = 0; ft < 4; ++ft)   // B-frag: col = lr, k = kt*32 + lg*8 + j
            bfr[ft] = *reinterpret_cast<const short8*>(
                Wb + (size_t)(wc * 64 + ft * 16 + lr) * NA_ + kt * 32 + lg * 8);
        #pragma unroll
        for (int m = 0; m < 4; ++m) {
            int row = wr * 64 + m * 16 + lr;       // A-frag: row = lr, k = kt*32 + lg*8 + j
            int byte = (row * 256 + kt * 64 + lg * 16) ^ ((row & 7) << 4);
            short8 afr = *reinterpret_cast<const short8*>(
                reinterpret_cast<const char*>(albuf) + byte);
            #pragma unroll
            for (int ft = 0; ft < 4; ++ft)
                acc[m][ft] = __builtin_amdgcn_mfma_f32_16x16x32_bf16(afr, bfr[ft], acc[m][ft], 0, 0, 0);
        }
    }

    // ---- BN stats: intra-wave 64-row partials, cross-wr via LDS
    float rs[4], sh[4];
    #pragma unroll
    for (int ft = 0; ft < 4; ++ft) {
        float s = 0.f, q = 0.f;
        #pragma unroll
        for (int m = 0; m < 4; ++m)
            #pragma unroll
            for (int r = 0; r < 4; ++r) {
                float v = acc[m][ft][r];
                s += v; q = fmaf(v, v, q);
            }
        s += __shfl_xor(s, 16, 64); s += __shfl_xor(s, 32, 64);
        q += __shfl_xor(q, 16, 64); q += __shfl_xor(q, 32, 64);
        if (lg == 0) { sbuf[wr][wc][ft][lr] = s; qbuf[wr][wc][ft][lr] = q; }
    }
    __syncthreads();
    #pragma unroll
    for (int ft = 0; ft < 4; ++ft) {
        float s = sbuf[0][wc][ft][lr] + sbuf[1][wc][ft][lr];
        float q = qbuf[0][wc][ft][lr] + qbuf[1][wc][ft][lr];
        int f = wc * 64 + ft * 16 + lr;
        float mean = s * (1.f / VBS_);
        float var  = q * (1.f / VBS_) - mean * mean;
        rs[ft] = rsqrtf(var + EPS_) * bnw[f];
        sh[ft] = fmaf(-mean, rs[ft], bnb[f]);
    }

    // ---- read prior (C/D layout), z = (x*rs+sh)*p; pack z,p bf16; row sum/max
    uint2 zpk[4][4], ppk[4][4];                    // [m][ft]: .x packs r0|r1, .y packs r2|r3
    #pragma unroll
    for (int m = 0; m < 4; ++m) {
        const float* prow = prior + (rowbase + wr * 64 + m * 16 + lg * 4) * F_;
        float rsum_[4] = {0.f, 0.f, 0.f, 0.f};
        float rmax_[4] = {-3.4e38f, -3.4e38f, -3.4e38f, -3.4e38f};
        #pragma unroll
        for (int ft = 0; ft < 4; ++ft) {
            int col = wc * 64 + ft * 16 + lr;
            float p0 = prow[col], p1 = prow[F_ + col], p2 = prow[2 * F_ + col], p3 = prow[3 * F_ + col];
            uint2 pk;
            pk.x = f2bf(p0) | (f2bf(p1) << 16);
            pk.y = f2bf(p2) | (f2bf(p3) << 16);
            ppk[m][ft] = pk;
            float z0 = fmaf(acc[m][ft][0], rs[ft], sh[ft]) * bflo(pk.x);
            float z1 = fmaf(acc[m][ft][1], rs[ft], sh[ft]) * bfhi(pk.x);
            float z2 = fmaf(acc[m][ft][2], rs[ft], sh[ft]) * bflo(pk.y);
            float z3 = fmaf(acc[m][ft][3], rs[ft], sh[ft]) * bfhi(pk.y);
            uint2 zk;
            zk.x = f2bf(z0) | (f2bf(z1) << 16);
            zk.y = f2bf(z2) | (f2bf(z3) << 16);
            zpk[m][ft] = zk;
            rsum_[0] += z0; rmax_[0] = fmaxf(rmax_[0], z0);
            rsum_[1] += z1; rmax_[1] = fmaxf(rmax_[1], z1);
            rsum_[2] += z2; rmax_[2] = fmaxf(rmax_[2], z2);
            rsum_[3] += z3; rmax_[3] = fmaxf(rmax_[3], z3);
        }
        #pragma unroll
        for (int r = 0; r < 4; ++r) {
            float s = rsum_[r], mx = rmax_[r];
            #pragma unroll
            for (int d = 1; d < 16; d <<= 1) {
                s += __shfl_xor(s, d, 64);
                mx = fmaxf(mx, __shfl_xor(mx, d, 64));
            }
            if (lr == 0) {
                int row = wr * 64 + m * 16 + lg * 4 + r;
                rowsum[row][wc] = s; rowmax[row][wc] = mx;
            }
        }
    }
    __syncthreads();

    // ---- tau per row (fast path: k_z = 255)
    if (tid < VBS_) {
        float s  = rowsum[tid][0] + rowsum[tid][1] + rowsum[tid][2] + rowsum[tid][3];
        float mx = fmaxf(fmaxf(rowmax[tid][0], rowmax[tid][1]),
                         fmaxf(rowmax[tid][2], rowmax[tid][3]));
        if (1.0f + 255.0f * mx - s > 0.0f) {
            tau_s[tid] = (s + 1.0f) * (1.0f / 255.0f);
        } else {
            tau_s[tid] = __int_as_float(0x7fc00000);   // NaN marker
            atomicAdd(&nflag, 1);
        }
    }
    __syncthreads();

    // ---- slow path: faithful sorted algorithm (block-uniform, rare/never)
    if (nflag > 0) {
        for (int row = 0; row < VBS_; ++row) {
            float tv = tau_s[row];
            if (tv == tv) continue;                // uniform (same LDS value)
            #pragma unroll
            for (int mm = 0; mm < 4; ++mm)
                #pragma unroll
                for (int rr = 0; rr < 4; ++rr)
                    if (wr * 64 + mm * 16 + lg * 4 + rr == row) {
                        #pragma unroll
                        for (int ft = 0; ft < 4; ++ft) {
                            uint2 zk = zpk[mm][ft];
                            float zv = (rr == 0) ? bflo(zk.x) : (rr == 1) ? bfhi(zk.x)
                                     : (rr == 2) ? bflo(zk.y) : bfhi(zk.y);
                            zrow[wc * 64 + ft * 16 + lr] = zv;
                        }
                    }
            __syncthreads();
            if (tid == 0) {
                for (int i = 1; i < F_; ++i) {     // insertion sort ascending
                    float key = zrow[i]; int j = i - 1;
                    while (j >= 0 && zrow[j] > key) { zrow[j + 1] = zrow[j]; --j; }
                    zrow[j + 1] = key;
                }
                float cs = 0.f; int kz = 0;
                for (int j = 0; j < F_; ++j) {
                    cs += zrow[j];
                    if (1.0f + (float)j * zrow[j] - cs > 0.0f) kz = j;
                }
                float mz = 0.f;
                for (int j = 0; j <= kz; ++j) mz += zrow[j];
                tau_s[row] = (mz + 1.0f) / (float)kz;   // kz==0 -> inf -> m=0 (clip)
            }
            __syncthreads();
        }
    }
    __syncthreads();

    // ---- outputs: m = relu(z - tau); new_prior = p * (1.5 - m)
    #pragma unroll
    for (int m = 0; m < 4; ++m) {
        int row0 = wr * 64 + m * 16 + lg * 4;
        float t0 = tau_s[row0], t1 = tau_s[row0 + 1], t2 = tau_s[row0 + 2], t3 = tau_s[row0 + 3];
        size_t gb = (rowbase + row0) * F_;
        #pragma unroll
        for (int ft = 0; ft < 4; ++ft) {
            int col = wc * 64 + ft * 16 + lr;
            uint2 pk = ppk[m][ft], zk = zpk[m][ft];
            float p0 = bflo(pk.x), p1 = bfhi(pk.x), p2 = bflo(pk.y), p3 = bfhi(pk.y);
            float z0 = bflo(zk.x), z1 = bfhi(zk.x), z2 = bflo(zk.y), z3 = bfhi(zk.y);
            float m0 = fmaxf(z0 - t0, 0.f), m1 = fmaxf(z1 - t1, 0.f);
            float m2 = fmaxf(z2 - t2, 0.f), m3 = fmaxf(z3 - t3, 0.f);
            out_m[gb + col]           = m0;
            out_m[gb + F_ + col]      = m1;
            out_m[gb + 2 * F_ + col]  = m2;
            out_m[gb + 3 * F_ + col]  = m3;
            out_np[gb + col]          = p0 * (GAMMA_ - m0);
            out_np[gb + F_ + col]     = p1 * (GAMMA_ - m1);
            out_np[gb + 2 * F_ + col] = p2 * (GAMMA_ - m2);
            out_np[gb + 3 * F_ + col] = p3 * (GAMMA_ - m3);
        }
    }
}

extern "C" void kernel_launch(void* const* d_in, const int* in_sizes, int n_in,
                              void* d_out, int out_size, void* d_ws, size_t ws_size,
                              hipStream_t stream) {
    const float* a     = (const float*)d_in[0];
    const float* prior = (const float*)d_in[1];
    const float* W     = (const float*)d_in[2];
    const float* bnw   = (const float*)d_in[4];
    const float* bnb   = (const float*)d_in[5];
    const int N = in_sizes[0] / NA_;
    const int nchunks = N / VBS_;
    float* out_m  = (float*)d_out;
    float* out_np = out_m + (size_t)N * F_;

    unsigned short* Wb = (unsigned short*)d_ws;    // 64 KB (ws proven >= 131 MB)
    k0_cvt_w<<<(F_ * NA_ / 4 + 255) / 256, 256, 0, stream>>>(W, Wb);
    k_fused<<<nchunks, 512, 0, stream>>>(a, Wb, bnw, bnb, prior, out_m, out_np);
}

// Round 4
// 110.901 us; speedup vs baseline: 1.4048x; 1.4048x over previous
//
#include <hip/hip_runtime.h>
#include <math.h>

#define NA_ 128
#define F_ 256
#define VBS_ 128
#define GAMMA_ 1.5f
#define EPS_ 1e-5f

typedef __attribute__((ext_vector_type(8))) short short8;
typedef __attribute__((ext_vector_type(4))) float f32x4;

static __device__ __forceinline__ unsigned f2bf(float f) {
    unsigned u = __float_as_uint(f);
    return (u + 0x7FFFu + ((u >> 16) & 1u)) >> 16;   // RNE bf16
}
static __device__ __forceinline__ float bflo(unsigned u) { return __uint_as_float(u << 16); }

// ---------------- kernel 0: W f32 -> bf16 (64 KB, one-time) ----------------
__global__ void k0_cvt_w(const float* __restrict__ W, unsigned short* __restrict__ Wb) {
    int i = blockIdx.x * 256 + threadIdx.x;          // 8192 groups of 4
    float4 v = reinterpret_cast<const float4*>(W)[i];
    uint2 o;
    o.x = f2bf(v.x) | (f2bf(v.y) << 16);
    o.y = f2bf(v.z) | (f2bf(v.w) << 16);
    reinterpret_cast<uint2*>(Wb)[i] = o;
}

// ---------------- fully fused: GEMM + ghost-BN + sparsemax + outputs ----------------
// block = one virtual-batch chunk (128 rows), 512 threads = 8 waves (2 row-halves x 4 col-quarters)
// Epilogue: znorm (bf16) goes through LDS column-major; wave-per-row coalesced I/O.
__global__ __launch_bounds__(512, 4) void k_fused(
    const float* __restrict__ a, const unsigned short* __restrict__ Wb,
    const float* __restrict__ bnw, const float* __restrict__ bnb,
    const float* __restrict__ prior,
    float* __restrict__ out_m, float* __restrict__ out_np)
{
    // zlds: column-major znorm, 256 cols x 32 row-groups(4 rows bf16 packed in 8B) = 64 KB.
    // slot(col, rg) = rg ^ (col&31) ^ ((col>>2)&31):
    //   write (cols via lr): >= minimal rounds (4 lanes/slot on a 512B wave write)
    //   read  (cols = 4*lane+c, fixed row): injective in lane&31 -> 2-way only = free
    __shared__ unsigned long long zlds[F_ * 32];
    __shared__ float sbuf[2][4][4][16];            // BN partial sums  [wr][wc][ft][lr]
    __shared__ float qbuf[2][4][4][16];            // BN partial sumsq
    __shared__ float zrow[8][F_];                  // per-wave slow-path sort buffer

    unsigned short* albuf = reinterpret_cast<unsigned short*>(zlds);  // first 32 KB: A-tile

    const int tid = threadIdx.x;
    const int lane = tid & 63, wid = tid >> 6;
    const int wr = wid >> 2, wc = wid & 3;         // wave = (row-half, col-quarter)
    const int lr = lane & 15, lg = lane >> 4;
    const size_t rowbase = (size_t)blockIdx.x * VBS_;

    // ---- stage a (f32) -> bf16 LDS (A-tile region), swizzle byte ^= ((row&7)<<4)
    #pragma unroll
    for (int i = 0; i < 4; ++i) {
        int seg = tid + 512 * i;                   // 2048 segs of 8 elems
        int row = seg >> 4, ks = seg & 15;
        const float4* g = reinterpret_cast<const float4*>(a + (rowbase + row) * NA_ + ks * 8);
        float4 v0 = g[0], v1 = g[1];
        uint4 pk;
        pk.x = f2bf(v0.x) | (f2bf(v0.y) << 16);
        pk.y = f2bf(v0.z) | (f2bf(v0.w) << 16);
        pk.z = f2bf(v1.x) | (f2bf(v1.y) << 16);
        pk.w = f2bf(v1.z) | (f2bf(v1.w) << 16);
        int byte = (row * 256 + ks * 16) ^ ((row & 7) << 4);
        *reinterpret_cast<uint4*>(reinterpret_cast<char*>(albuf) + byte) = pk;
    }
    __syncthreads();

    // ---- MFMA: wave computes rows [wr*64, +64) x cols [wc*64, +64)
    f32x4 acc[4][4];
    #pragma unroll
    for (int m = 0; m < 4; ++m)
        #pragma unroll
        for (int ft = 0; ft < 4; ++ft)
            acc[m][ft] = (f32x4){0.f, 0.f, 0.f, 0.f};

    // linear bias b cancels through BN -> skipped
    #pragma unroll
    for (int kt = 0; kt < 4; ++kt) {
        short8 bfr[4];
        #pragma unroll
        for (int ft = 0; ft < 4; ++ft)   // B-frag: col = lr, k = kt*32 + lg*8 + j
            bfr[ft] = *reinterpret_cast<const short8*>(
                Wb + (size_t)(wc * 64 + ft * 16 + lr) * NA_ + kt * 32 + lg * 8);
        #pragma unroll
        for (int m = 0; m < 4; ++m) {
            int row = wr * 64 + m * 16 + lr;       // A-frag: row = lr, k = kt*32 + lg*8 + j
            int byte = (row * 256 + kt * 64 + lg * 16) ^ ((row & 7) << 4);
            short8 afr = *reinterpret_cast<const short8*>(
                reinterpret_cast<const char*>(albuf) + byte);
            #pragma unroll
            for (int ft = 0; ft < 4; ++ft)
                acc[m][ft] = __builtin_amdgcn_mfma_f32_16x16x32_bf16(afr, bfr[ft], acc[m][ft], 0, 0, 0);
        }
    }

    // ---- BN stats: intra-wave 64-row partials, cross-wr via LDS
    #pragma unroll
    for (int ft = 0; ft < 4; ++ft) {
        float s = 0.f, q = 0.f;
        #pragma unroll
        for (int m = 0; m < 4; ++m)
            #pragma unroll
            for (int r = 0; r < 4; ++r) {
                float v = acc[m][ft][r];
                s += v; q = fmaf(v, v, q);
            }
        s += __shfl_xor(s, 16, 64); s += __shfl_xor(s, 32, 64);
        q += __shfl_xor(q, 16, 64); q += __shfl_xor(q, 32, 64);
        if (lg == 0) { sbuf[wr][wc][ft][lr] = s; qbuf[wr][wc][ft][lr] = q; }
    }
    __syncthreads();   // also guarantees all A-tile reads done before zlds overwrite

    float rs[4], sh[4];
    #pragma unroll
    for (int ft = 0; ft < 4; ++ft) {
        float s = sbuf[0][wc][ft][lr] + sbuf[1][wc][ft][lr];
        float q = qbuf[0][wc][ft][lr] + qbuf[1][wc][ft][lr];
        int f = wc * 64 + ft * 16 + lr;
        float mean = s * (1.f / VBS_);
        float var  = q * (1.f / VBS_) - mean * mean;
        rs[ft] = rsqrtf(var + EPS_) * bnw[f];
        sh[ft] = fmaf(-mean, rs[ft], bnb[f]);
    }

    // ---- BN-apply; pack 4 rows bf16 -> column-major swizzled zlds (b64 writes)
    #pragma unroll
    for (int m = 0; m < 4; ++m) {
        int rg = wr * 16 + m * 4 + lg;             // row-group = rows [rg*4, rg*4+4)
        #pragma unroll
        for (int ft = 0; ft < 4; ++ft) {
            int col = wc * 64 + ft * 16 + lr;
            float z0 = fmaf(acc[m][ft][0], rs[ft], sh[ft]);
            float z1 = fmaf(acc[m][ft][1], rs[ft], sh[ft]);
            float z2 = fmaf(acc[m][ft][2], rs[ft], sh[ft]);
            float z3 = fmaf(acc[m][ft][3], rs[ft], sh[ft]);
            uint2 zk;
            zk.x = f2bf(z0) | (f2bf(z1) << 16);
            zk.y = f2bf(z2) | (f2bf(z3) << 16);
            int slot = (rg ^ (col & 31) ^ ((col >> 2) & 31)) & 31;
            zlds[col * 32 + slot] = *reinterpret_cast<unsigned long long*>(&zk);
        }
    }
    __syncthreads();

    // ---- wave-per-row epilogue: coalesced prior read, tau, coalesced stores
    const int row0 = wid * 16;
    float4 p_next = reinterpret_cast<const float4*>(prior + (rowbase + row0) * F_)[lane];
    for (int rr = 0; rr < 16; ++rr) {
        const int row = row0 + rr;
        float4 p = p_next;
        if (rr < 15)
            p_next = reinterpret_cast<const float4*>(prior + (rowbase + row + 1) * F_)[lane];

        const int rg = row >> 2, rp = row & 3;
        float pv[4] = {p.x, p.y, p.z, p.w};
        float z[4];
        #pragma unroll
        for (int c = 0; c < 4; ++c) {
            int col = 4 * lane + c;
            int slot = (rg ^ (col & 31) ^ (lane & 31)) & 31;   // (col>>2)&31 == lane&31
            unsigned short zn = *reinterpret_cast<const unsigned short*>(
                reinterpret_cast<const char*>(zlds) + col * 256 + slot * 8 + rp * 2);
            z[c] = bflo(zn) * pv[c];
        }

        float s  = (z[0] + z[1]) + (z[2] + z[3]);
        float mx = fmaxf(fmaxf(z[0], z[1]), fmaxf(z[2], z[3]));
        #pragma unroll
        for (int d = 1; d < 64; d <<= 1) {
            s += __shfl_xor(s, d, 64);
            mx = fmaxf(mx, __shfl_xor(mx, d, 64));
        }

        float tau;
        if (1.0f + 255.0f * mx - s > 0.0f) {
            // w[255] true -> k_z = 255, m_z = full sum (fast path, ~always for BN'd data)
            tau = (s + 1.0f) * (1.0f / 255.0f);
        } else {
            // faithful sorted algorithm, wave-uniform branch, wave-local
            float* sr = zrow[wid];
            #pragma unroll
            for (int c = 0; c < 4; ++c) sr[4 * lane + c] = z[c];
            __asm__ volatile("s_waitcnt lgkmcnt(0)" ::: "memory");
            float t0 = 0.f;
            if (lane == 0) {
                for (int i = 1; i < F_; ++i) {     // insertion sort ascending
                    float key = sr[i]; int j = i - 1;
                    while (j >= 0 && sr[j] > key) { sr[j + 1] = sr[j]; --j; }
                    sr[j + 1] = key;
                }
                float cs = 0.f; int kz = 0;
                for (int j = 0; j < F_; ++j) {
                    cs += sr[j];
                    if (1.0f + (float)j * sr[j] - cs > 0.0f) kz = j;
                }
                float mz = 0.f;
                for (int j = 0; j <= kz; ++j) mz += sr[j];
                t0 = (mz + 1.0f) / (float)kz;      // kz==0 -> inf -> m=0 (matches clip)
            }
            tau = __shfl(t0, 0, 64);
        }

        float m0 = fmaxf(z[0] - tau, 0.f), m1 = fmaxf(z[1] - tau, 0.f);
        float m2 = fmaxf(z[2] - tau, 0.f), m3 = fmaxf(z[3] - tau, 0.f);
        float4 om = {m0, m1, m2, m3};
        float4 on = {pv[0] * (GAMMA_ - m0), pv[1] * (GAMMA_ - m1),
                     pv[2] * (GAMMA_ - m2), pv[3] * (GAMMA_ - m3)};
        reinterpret_cast<float4*>(out_m  + (rowbase + row) * F_)[lane] = om;
        reinterpret_cast<float4*>(out_np + (rowbase + row) * F_)[lane] = on;
    }
}

extern "C" void kernel_launch(void* const* d_in, const int* in_sizes, int n_in,
                              void* d_out, int out_size, void* d_ws, size_t ws_size,
                              hipStream_t stream) {
    const float* a     = (const float*)d_in[0];
    const float* prior = (const float*)d_in[1];
    const float* W     = (const float*)d_in[2];
    const float* bnw   = (const float*)d_in[4];
    const float* bnb   = (const float*)d_in[5];
    const int N = in_sizes[0] / NA_;
    const int nchunks = N / VBS_;
    float* out_m  = (float*)d_out;
    float* out_np = out_m + (size_t)N * F_;

    unsigned short* Wb = (unsigned short*)d_ws;    // 64 KB in workspace
    k0_cvt_w<<<(F_ * NA_ / 4 + 255) / 256, 256, 0, stream>>>(W, Wb);
    k_fused<<<nchunks, 512, 0, stream>>>(a, Wb, bnw, bnb, prior, out_m, out_np);
}